// Round 10
// baseline (311.443 us; speedup 1.0000x reference)
//
#include <hip/hip_runtime.h>
#include <hip/hip_bf16.h>
#include <stdint.h>

// EvolvedLoopLinear: out[b,j] = sum_i x[b,i]*W[j,i] + b[j]
// M=8192, N=4096, K=4096. fp32 in/out, bf16 MFMA compute.
// Round 10: 256x256 tile, BK=32, TRIPLE-buffered LDS (96 KiB), ONE barrier
// per K-tile (no intra-tile barriers). Stage target = buffer whose readers
// finished a full tile ago (distance-2 triple rotation) => WAR covered by
// the single tile-boundary barrier; RAW by counted vmcnt(4). Within the
// barrier-free window, waves desynchronize: one wave's 12 ds_reads overlap
// the other's 32-MFMA cluster on the same SIMD (the overlap the per-phase
// lockstep could not express). No explicit lgkmcnt (compiler counted
// waits, r9). Fence discipline pins gld_lds issue order (r4). T1 XCD
// swizzle, T2 chunk-XOR swizzle, T4 counted vmcnt, T5 setprio.

typedef __bf16 bf16_t;
typedef __bf16 bf16x8 __attribute__((ext_vector_type(8)));
typedef float  f32x4  __attribute__((ext_vector_type(4)));

#define M_DIM 8192
#define N_DIM 4096
#define K_DIM 4096
#define NT    (K_DIM / 32)   // 128 K-tiles of BK=32

#define GLD16(gp, lp) __builtin_amdgcn_global_load_lds(                    \
    (const __attribute__((address_space(1))) void*)(gp),                   \
    (__attribute__((address_space(3))) void*)(lp), 16, 0, 0)

#define MFMA(a, b, c) __builtin_amdgcn_mfma_f32_16x16x32_bf16((a), (b), (c), 0, 0, 0)

#define FENCE() asm volatile("" ::: "memory")

// ---------------- fp32 -> bf16 convert (vectorized, grid-stride) -----------
__global__ void __launch_bounds__(256) cvt_f32_bf16(
    const float* __restrict__ in, bf16_t* __restrict__ out, long n8)
{
    long i0 = (long)blockIdx.x * blockDim.x + threadIdx.x;
    long stride = (long)gridDim.x * blockDim.x;
    for (long i = i0; i < n8; i += stride) {
        const float4* p = (const float4*)(in + i * 8);
        float4 a = p[0];
        float4 b = p[1];
        bf16x8 o;
        o[0] = (bf16_t)a.x; o[1] = (bf16_t)a.y; o[2] = (bf16_t)a.z; o[3] = (bf16_t)a.w;
        o[4] = (bf16_t)b.x; o[5] = (bf16_t)b.y; o[6] = (bf16_t)b.z; o[7] = (bf16_t)b.w;
        *(bf16x8*)(out + i * 8) = o;
    }
}

// ---------------- 256x256 bf16 GEMM, triple-buffer BK=32, 1 bar/tile ------
// Buffer q (16384 el = 32 KB): A 256x32 @ q*16384, B 256x32 @ +8192.
// Chunk swizzle: stored slot = chunk ^ (row&3) ^ ((row>>2)&3), 16B granules.
__global__ void __launch_bounds__(512, 1) gemm_256_tb(
    const bf16_t* __restrict__ A, const bf16_t* __restrict__ B,
    const float* __restrict__ bias, float* __restrict__ C)
{
    __shared__ bf16_t sm[3 * 16384];   // 96 KiB

    // XCD-aware bijective swizzle (gridDim = 512, divisible by 8)
    const int nwg = gridDim.x;
    const int bid = blockIdx.x;
    const int cpx = nwg >> 3;
    const int swz = (bid & 7) * cpx + (bid >> 3);
    const int NBN = N_DIM / 256;                       // 16
    const long blockM = (long)(swz / NBN) * 256;
    const long blockN = (long)(swz % NBN) * 256;

    const int t    = threadIdx.x;
    const int lane = t & 63;
    const int wid  = t >> 6;        // 8 waves: 2 (M) x 4 (N)
    const int wr   = wid >> 2;      // 0..1 -> 128 rows each
    const int wc   = wid & 3;       // 0..3 -> 64 cols each
    const int l15  = lane & 15;
    const int lk   = lane >> 4;     // 0..3

    // staging: LDS dest linear (t*16B); global src row = t>>2 (+128 on
    // line 1), stored global chunk = (t&3) ^ ((t>>2)&3) ^ ((t>>4)&3).
    const int cg = (t & 3) ^ ((t >> 2) & 3) ^ ((t >> 4) & 3);
    const bf16_t* gA = A + (blockM + (t >> 2)) * (long)K_DIM + cg * 8;
    const bf16_t* gB = B + (blockN + (t >> 2)) * (long)K_DIM + cg * 8;
    const int dstT = t * 8;         // 16 B per thread, linear

    // read side: fragment row = base16 + l15 -> swizzle depends on l15 only
    const int swzr = (l15 & 3) ^ ((l15 >> 2) & 3);
    const int cOff = (lk ^ swzr) << 3;
    const int aBase = (wr * 128 + l15) * 32 + cOff;          // + m*512
    const int bBase = 8192 + (wc * 64 + l15) * 32 + cOff;    // + n*512

    f32x4 acc[8][4] = {};

#define STAGE_A(q, tk) do {                                                \
    const bf16_t* _g = gA + (long)(tk) * 32;                               \
    bf16_t* _l = (bf16_t*)sm + (q) * 16384 + dstT;                         \
    GLD16(_g,                _l);                                          \
    GLD16(_g + 128L * K_DIM, _l + 4096); } while (0)

#define STAGE_B(q, tk) do {                                                \
    const bf16_t* _g = gB + (long)(tk) * 32;                               \
    bf16_t* _l = (bf16_t*)sm + (q) * 16384 + 8192 + dstT;                  \
    GLD16(_g,                _l);                                          \
    GLD16(_g + 128L * K_DIM, _l + 4096); } while (0)

    // prologue: tile0 -> buf0, tile1 -> buf1 (fence-pinned issue order)
    STAGE_A(0, 0); STAGE_B(0, 0);
    FENCE();
    STAGE_A(1, 1); STAGE_B(1, 1);
    FENCE();
    asm volatile("s_waitcnt vmcnt(4)" ::: "memory");   // tile0 landed
    __builtin_amdgcn_sched_barrier(0);
    __builtin_amdgcn_s_barrier();
    FENCE();

    int r = 0, r2 = 2;   // compute buffer, stage buffer (= (tk+2)%3)
    for (int tk = 0; tk < NT; ++tk) {
        const bf16_t* sA = (const bf16_t*)sm + r * 16384;

        // stage tile tk+2 into the buffer whose readers finished at the
        // END of tile tk-1 (one full tile + barrier ago)
        if (tk + 2 < NT) { STAGE_A(r2, tk + 2); STAGE_B(r2, tk + 2); }
        FENCE();

        // barrier-free window: 12 ds_reads + 32 MFMA, compiler pipelines;
        // waves on a SIMD desynchronize -> DS overlaps MFMA across waves.
        bf16x8 b[4], a[8];
#pragma unroll
        for (int n = 0; n < 4; ++n) b[n] = *(const bf16x8*)(sA + bBase + n * 512);
#pragma unroll
        for (int m = 0; m < 8; ++m) a[m] = *(const bf16x8*)(sA + aBase + m * 512);
        __builtin_amdgcn_s_setprio(1);
#pragma unroll
        for (int m = 0; m < 8; ++m)
#pragma unroll
            for (int n = 0; n < 4; ++n)
                acc[m][n] = MFMA(a[m], b[n], acc[m][n]);
        __builtin_amdgcn_s_setprio(0);

        // counted drain: tk+1's 4 loads land; tk+2's 4 stay in flight
        if (tk < NT - 2) asm volatile("s_waitcnt vmcnt(4)" ::: "memory");
        else             asm volatile("s_waitcnt vmcnt(0)" ::: "memory");
        __builtin_amdgcn_sched_barrier(0);
        __builtin_amdgcn_s_barrier();
        FENCE();

        r  = (r  == 2) ? 0 : r  + 1;
        r2 = (r2 == 2) ? 0 : r2 + 1;
    }

#undef STAGE_A
#undef STAGE_B

    // epilogue: C/D layout col = lane&15, row = (lane>>4)*4 + j
    const long cb = blockN + wc * 64;
    float bv[4];
    long  cn[4];
#pragma unroll
    for (int n = 0; n < 4; ++n) {
        cn[n] = cb + n * 16 + l15;
        bv[n] = bias[cn[n]];
    }
#pragma unroll
    for (int m = 0; m < 8; ++m) {
        const long r0 = blockM + wr * 128 + m * 16 + lk * 4;
#pragma unroll
        for (int n = 0; n < 4; ++n)
#pragma unroll
            for (int j = 0; j < 4; ++j)
                C[(r0 + j) * (long)N_DIM + cn[n]] = acc[m][n][j] + bv[n];
    }
}

// ---------------- fp32 fallback (only if ws too small) ---------------------
__global__ void __launch_bounds__(256) gemm_f32_fallback(
    const float* __restrict__ A, const float* __restrict__ W,
    const float* __restrict__ bias, float* __restrict__ C)
{
    __shared__ float sA[64][17];
    __shared__ float sB[64][17];
    const int bm = blockIdx.y, bn = blockIdx.x;
    const int t = threadIdx.x;
    const int tx = t & 15, ty = t >> 4;
    const long row0 = (long)bm * 64, col0 = (long)bn * 64;
    float acc[4][4] = {};
    for (int kt = 0; kt < K_DIM; kt += 16) {
        const int r = t >> 2, c = (t & 3) * 4;
        float4 a4 = *(const float4*)&A[(row0 + r) * K_DIM + kt + c];
        float4 b4 = *(const float4*)&W[(col0 + r) * K_DIM + kt + c];
        sA[r][c] = a4.x; sA[r][c + 1] = a4.y; sA[r][c + 2] = a4.z; sA[r][c + 3] = a4.w;
        sB[r][c] = b4.x; sB[r][c + 1] = b4.y; sB[r][c + 2] = b4.z; sB[r][c + 3] = b4.w;
        __syncthreads();
#pragma unroll
        for (int kk = 0; kk < 16; ++kk) {
            float av[4], bv[4];
#pragma unroll
            for (int i = 0; i < 4; ++i) av[i] = sA[ty * 4 + i][kk];
#pragma unroll
            for (int j = 0; j < 4; ++j) bv[j] = sB[tx * 4 + j][kk];
#pragma unroll
            for (int i = 0; i < 4; ++i)
#pragma unroll
                for (int j = 0; j < 4; ++j) acc[i][j] += av[i] * bv[j];
        }
        __syncthreads();
    }
#pragma unroll
    for (int i = 0; i < 4; ++i)
#pragma unroll
        for (int j = 0; j < 4; ++j)
            C[(row0 + ty * 4 + i) * N_DIM + col0 + tx * 4 + j] =
                acc[i][j] + bias[col0 + tx * 4 + j];
}

extern "C" void kernel_launch(void* const* d_in, const int* in_sizes, int n_in,
                              void* d_out, int out_size, void* d_ws, size_t ws_size,
                              hipStream_t stream)
{
    const float* x = (const float*)d_in[0];   // [8192, 4096]
    const float* W = (const float*)d_in[1];   // [4096, 4096]
    const float* b = (const float*)d_in[2];   // [4096]
    float* out = (float*)d_out;               // [8192, 4096] fp32

    const long xe = (long)M_DIM * K_DIM;
    const long we = (long)N_DIM * K_DIM;
    const size_t need = (size_t)(xe + we) * sizeof(bf16_t);  // ~96 MiB

    if (ws_size >= need) {
        bf16_t* xb = (bf16_t*)d_ws;
        bf16_t* wb = xb + xe;
        cvt_f32_bf16<<<2048, 256, 0, stream>>>(x, xb, xe / 8);
        cvt_f32_bf16<<<1024, 256, 0, stream>>>(W, wb, we / 8);
        gemm_256_tb<<<(M_DIM / 256) * (N_DIM / 256), 512, 0, stream>>>(xb, wb, b, out);
    } else {
        dim3 grid(N_DIM / 64, M_DIM / 64);
        gemm_f32_fallback<<<grid, 256, 0, stream>>>(x, W, b, out);
    }
}